// Round 1
// baseline (87.357 us; speedup 1.0000x reference)
//
#include <hip/hip_runtime.h>
#include <math.h>

namespace {
constexpr int kB = 4, kT = 256, kS = 512, kH = 12, kD = 768, kV = 32000;
constexpr int HASH = 1024;   // 512 inserts, load factor 0.5
constexpr int NT = 256;

__global__ __launch_bounds__(NT) void pg_kernel(
    const float* __restrict__ dec_output,   // B,T,D
    const float* __restrict__ final_output, // B,T,V
    const float* __restrict__ attn_w,       // B,H,T,S
    const float* __restrict__ W_pgen,       // D
    const float* __restrict__ b_pgen,       // 1
    const int*   __restrict__ enc,          // B,S
    float* __restrict__ out)                // B,T,V
{
  const int bt  = blockIdx.x;
  const int b   = bt / kT;
  const int t   = bt - b * kT;
  const int tid = threadIdx.x;

  __shared__ float red[NT];
  __shared__ float upd[kS];
  __shared__ int   hkey[HASH];
  __shared__ float hval[HASH];
  __shared__ float s_pgen, s_M, s_Z, s_base;

  // ---- Phase A: p_gen = sigmoid(dec[b,t,:] . W_pgen + b_pgen) ----
  {
    const float* dec = dec_output + (size_t)bt * kD;
    float acc = 0.f;
    for (int i = tid; i < kD; i += NT) acc += dec[i] * W_pgen[i];
    red[tid] = acc;
    __syncthreads();
    for (int off = NT / 2; off > 0; off >>= 1) {
      if (tid < off) red[tid] += red[tid + off];
      __syncthreads();
    }
    if (tid == 0) {
      float z = red[0] + b_pgen[0];
      s_pgen = 1.f / (1.f + expf(-z));
    }
  }
  // hash init (the trailing barrier also publishes s_pgen)
  for (int i = tid; i < HASH; i += NT) { hkey[i] = -1; hval[i] = 0.f; }
  __syncthreads();

  // ---- Phase B: attn = mean_h A[b,h,t,:]; softmax over S; scale by (1-p_gen) ----
  {
    float a0 = 0.f, a1 = 0.f;           // s = tid, s = tid + 256
    #pragma unroll
    for (int h = 0; h < kH; ++h) {
      const float* ap = attn_w + (((size_t)b * kH + h) * kT + t) * kS;
      a0 += ap[tid];
      a1 += ap[tid + NT];
    }
    constexpr float invH = 1.f / kH;
    a0 *= invH; a1 *= invH;
    red[tid] = fmaxf(a0, a1);
    __syncthreads();
    for (int off = NT / 2; off > 0; off >>= 1) {
      if (tid < off) red[tid] = fmaxf(red[tid], red[tid + off]);
      __syncthreads();
    }
    float mx = red[0];
    __syncthreads();
    float e0 = __expf(a0 - mx), e1 = __expf(a1 - mx);
    red[tid] = e0 + e1;
    __syncthreads();
    for (int off = NT / 2; off > 0; off >>= 1) {
      if (tid < off) red[tid] += red[tid + off];
      __syncthreads();
    }
    float scale = (1.f - s_pgen) / red[0];
    upd[tid]      = e0 * scale;
    upd[tid + NT] = e1 * scale;
  }
  __syncthreads();

  // ---- Phase C: scatter updates into LDS hash keyed by token ----
  {
    const int* ep = enc + b * kS;
    for (int s = tid; s < kS; s += NT) {
      int key   = ep[s];
      float val = upd[s];
      unsigned hpos = ((unsigned)key * 2654435761u) >> 22;   // 10 top bits
      while (true) {
        int prev = atomicCAS(&hkey[hpos], -1, key);
        if (prev == -1 || prev == key) { atomicAdd(&hval[hpos], val); break; }
        hpos = (hpos + 1) & (HASH - 1);
      }
    }
  }
  __syncthreads();

  // ---- Phase D: online softmax stats (M, Z) over the 32000-wide row ----
  const float* xrow = final_output + (size_t)bt * kV;
  {
    const float4* x4 = (const float4*)xrow;
    float m = -1e30f, ssum = 0.f;
    for (int f = tid; f < kV / 4; f += NT) {
      float4 x = x4[f];
      float m4 = fmaxf(fmaxf(x.x, x.y), fmaxf(x.z, x.w));
      if (m4 > m) { ssum *= __expf(m - m4); m = m4; }
      ssum += __expf(x.x - m) + __expf(x.y - m) + __expf(x.z - m) + __expf(x.w - m);
    }
    red[tid] = m; upd[tid] = ssum;   // upd reused as the s-array
    __syncthreads();
    for (int off = NT / 2; off > 0; off >>= 1) {
      if (tid < off) {
        float m1 = red[tid], m2 = red[tid + off];
        float s1 = upd[tid], s2 = upd[tid + off];
        float mm = fmaxf(m1, m2);
        red[tid] = mm;
        upd[tid] = s1 * __expf(m1 - mm) + s2 * __expf(m2 - mm);
      }
      __syncthreads();
    }
    if (tid == 0) {
      s_M = red[0];
      s_Z = upd[0];
      s_base = logf(s_pgen) - red[0] - logf(upd[0]);
    }
    __syncthreads();
  }

  // ---- Phase E: dense output. log(p_gen*softmax(x)) = x + base ----
  {
    float base = s_base;
    const float4* x4 = (const float4*)xrow;
    float4* o4 = (float4*)(out + (size_t)bt * kV);
    for (int f = tid; f < kV / 4; f += NT) {
      float4 x = x4[f];
      o4[f] = make_float4(x.x + base, x.y + base, x.z + base, x.w + base);
    }
  }
  __syncthreads();   // drains vmcnt before barrier -> fixup writes are ordered after

  // ---- Phase F: fixup the <=512 tokens that received copy probability ----
  {
    float pg = s_pgen, M = s_M, invZ = 1.f / s_Z;
    float* orow = out + (size_t)bt * kV;
    for (int i = tid; i < HASH; i += NT) {
      int key = hkey[i];
      if (key >= 0) {
        float c = hval[i];
        float x = xrow[key];
        orow[key] = logf(pg * expf(x - M) * invZ + c);
      }
    }
  }
}
}  // namespace

extern "C" void kernel_launch(void* const* d_in, const int* in_sizes, int n_in,
                              void* d_out, int out_size, void* d_ws, size_t ws_size,
                              hipStream_t stream) {
  const float* dec = (const float*)d_in[0];
  const float* fin = (const float*)d_in[1];
  const float* aw  = (const float*)d_in[2];
  const float* W   = (const float*)d_in[3];
  const float* bb  = (const float*)d_in[4];
  const int*   enc = (const int*)d_in[5];
  float* out = (float*)d_out;

  pg_kernel<<<dim3(kB * kT), dim3(NT), 0, stream>>>(dec, fin, aw, W, bb, enc, out);
}

// Round 3
// 80.721 us; speedup vs baseline: 1.0822x; 1.0822x over previous
//
#include <hip/hip_runtime.h>
#include <math.h>

namespace {
constexpr int kB = 4, kT = 256, kS = 512, kH = 12, kD = 768, kV = 32000;
constexpr int HASH = 1024;   // 512 inserts, load factor 0.5
constexpr int NT = 512;      // 8 waves/block * 4 blocks/CU = 32 waves/CU (max)
constexpr int NW = NT / 64;  // waves per block

typedef float f32x4 __attribute__((ext_vector_type(4)));

__device__ __forceinline__ float wave_sum(float v) {
  #pragma unroll
  for (int off = 32; off > 0; off >>= 1) v += __shfl_down(v, off, 64);
  return v;
}
__device__ __forceinline__ float wave_max(float v) {
  #pragma unroll
  for (int off = 32; off > 0; off >>= 1) v = fmaxf(v, __shfl_down(v, off, 64));
  return v;
}

__global__ __launch_bounds__(NT) void pg_kernel(
    const float* __restrict__ dec_output,   // B,T,D
    const float* __restrict__ final_output, // B,T,V
    const float* __restrict__ attn_w,       // B,H,T,S
    const float* __restrict__ W_pgen,       // D
    const float* __restrict__ b_pgen,       // 1
    const int*   __restrict__ enc,          // B,S
    float* __restrict__ out)                // B,T,V
{
  const int bt   = blockIdx.x;
  const int b    = bt / kT;
  const int t    = bt - b * kT;
  const int tid  = threadIdx.x;
  const int lane = tid & 63;
  const int wid  = tid >> 6;

  __shared__ float redm[NW], reds[NW];
  __shared__ float upd[kS];
  __shared__ int   hkey[HASH];
  __shared__ float hval[HASH];
  __shared__ float s_pgen, s_M, s_Z, s_base;

  // ---- Phase A: p_gen = sigmoid(dec[b,t,:] . W_pgen + b_pgen) ----
  {
    const float* dec = dec_output + (size_t)bt * kD;
    float acc = dec[tid] * W_pgen[tid];
    if (tid < kD - NT) acc += dec[tid + NT] * W_pgen[tid + NT];
    acc = wave_sum(acc);
    if (lane == 0) reds[wid] = acc;
  }
  // hash init (barrier below publishes reds too)
  for (int i = tid; i < HASH; i += NT) { hkey[i] = -1; hval[i] = 0.f; }
  __syncthreads();
  if (tid == 0) {
    float z = b_pgen[0];
    #pragma unroll
    for (int w = 0; w < NW; ++w) z += reds[w];
    s_pgen = 1.f / (1.f + expf(-z));
  }
  __syncthreads();

  // ---- Phase B: attn = mean_h A[b,h,t,:]; softmax over S; scale by (1-p_gen) ----
  {
    float a0 = 0.f;                      // one s element per thread (kS == NT)
    #pragma unroll
    for (int h = 0; h < kH; ++h) {
      const float* ap = attn_w + (((size_t)b * kH + h) * kT + t) * kS;
      a0 += ap[tid];
    }
    a0 *= (1.f / kH);
    float wm = wave_max(a0);
    if (lane == 0) redm[wid] = wm;
    __syncthreads();
    float mx = redm[0];
    #pragma unroll
    for (int w = 1; w < NW; ++w) mx = fmaxf(mx, redm[w]);
    float e0 = __expf(a0 - mx);
    float ws = wave_sum(e0);
    if (lane == 0) reds[wid] = ws;
    __syncthreads();
    float tot = 0.f;
    #pragma unroll
    for (int w = 0; w < NW; ++w) tot += reds[w];
    float scale = (1.f - s_pgen) / tot;
    upd[tid] = e0 * scale;
  }
  __syncthreads();

  // ---- Phase C: scatter updates into LDS hash keyed by token ----
  {
    const int* ep = enc + b * kS;
    int key   = ep[tid];
    float val = upd[tid];
    unsigned hpos = ((unsigned)key * 2654435761u) >> 22;   // 10 top bits
    while (true) {
      int prev = atomicCAS(&hkey[hpos], -1, key);
      if (prev == -1 || prev == key) { atomicAdd(&hval[hpos], val); break; }
      hpos = (hpos + 1) & (HASH - 1);
    }
  }
  __syncthreads();

  // ---- Phase D: online softmax stats (M, Z) over the 32000-wide row ----
  const float* xrow = final_output + (size_t)bt * kV;
  {
    const f32x4* x4 = (const f32x4*)xrow;
    float m = -1e30f, ssum = 0.f;
    for (int f = tid; f < kV / 4; f += NT) {
      f32x4 x = x4[f];
      float m4 = fmaxf(fmaxf(x.x, x.y), fmaxf(x.z, x.w));
      if (m4 > m) { ssum *= __expf(m - m4); m = m4; }
      ssum += __expf(x.x - m) + __expf(x.y - m) + __expf(x.z - m) + __expf(x.w - m);
    }
    // wave-level (m,s) merge
    #pragma unroll
    for (int off = 32; off > 0; off >>= 1) {
      float m2 = __shfl_down(m, off, 64);
      float s2 = __shfl_down(ssum, off, 64);
      float mm = fmaxf(m, m2);
      ssum = ssum * __expf(m - mm) + s2 * __expf(m2 - mm);
      m = mm;
    }
    if (lane == 0) { redm[wid] = m; reds[wid] = ssum; }
    __syncthreads();
    if (tid == 0) {
      float M = redm[0], Z = reds[0];
      #pragma unroll
      for (int w = 1; w < NW; ++w) {
        float mm = fmaxf(M, redm[w]);
        Z = Z * __expf(M - mm) + reds[w] * __expf(redm[w] - mm);
        M = mm;
      }
      s_M = M;
      s_Z = Z;
      s_base = logf(s_pgen) - M - logf(Z);
    }
    __syncthreads();
  }

  // ---- Phase E: dense output. log(p_gen*softmax(x)) = x + base ----
  {
    float base = s_base;
    const f32x4* x4 = (const f32x4*)xrow;
    f32x4* o4 = (f32x4*)(out + (size_t)bt * kV);
    for (int f = tid; f < kV / 4; f += NT) {
      f32x4 x = x4[f];
      f32x4 y = x + base;
      __builtin_nontemporal_store(y, &o4[f]);
    }
  }
  __syncthreads();   // drains vmcnt before barrier -> fixup writes are ordered after

  // ---- Phase F: fixup the <=512 tokens that received copy probability ----
  {
    float pg = s_pgen, M = s_M, invZ = 1.f / s_Z;
    float* orow = out + (size_t)bt * kV;
    for (int i = tid; i < HASH; i += NT) {
      int key = hkey[i];
      if (key >= 0) {
        float c = hval[i];
        float x = xrow[key];
        orow[key] = logf(pg * expf(x - M) * invZ + c);
      }
    }
  }
}
}  // namespace

extern "C" void kernel_launch(void* const* d_in, const int* in_sizes, int n_in,
                              void* d_out, int out_size, void* d_ws, size_t ws_size,
                              hipStream_t stream) {
  const float* dec = (const float*)d_in[0];
  const float* fin = (const float*)d_in[1];
  const float* aw  = (const float*)d_in[2];
  const float* W   = (const float*)d_in[3];
  const float* bb  = (const float*)d_in[4];
  const int*   enc = (const int*)d_in[5];
  float* out = (float*)d_out;

  pg_kernel<<<dim3(kB * kT), dim3(NT), 0, stream>>>(dec, fin, aw, W, bb, enc, out);
}